// Round 16
// baseline (1658.989 us; speedup 1.0000x reference)
//
#include <hip/hip_runtime.h>

typedef _Float16 half_t;
typedef _Float16 half8 __attribute__((ext_vector_type(8)));
typedef float f32x4 __attribute__((ext_vector_type(4)));
typedef unsigned long long u64;
typedef unsigned int u32;
typedef unsigned short u16;

#define GROUPS 16
#define WPG 8
#define NWG 128
#define THREADS 512
#define TSTEPS 512

// ws layout
#define W0_HALVES (8*8*10*64*8)    // 327680 halves
#define W1_HALVES (8*8*16*64*8)    // 524288 halves
#define X_HALVES  (512*16*1024)    // 8388608 halves
#define HX_U32    (2*GROUPS*4096)  // per layer: 2 slots x 16 groups x 4096 stamped u32

__device__ __forceinline__ float sigm(float x){ return 1.f/(1.f+__expf(-x)); }
__device__ __forceinline__ float tanh_fast(float x){ float e=__expf(2.f*x); return 1.f - 2.f/(e+1.f); }

// W0 blocks: [jw 0..63][kc 0..9][lane][8]; wave jw owns h [jw*4, jw*4+4)
__global__ void prep_w0(const float* __restrict__ Wih, const float* __restrict__ Whh,
                        half_t* __restrict__ dst){
  int idx = blockIdx.x*blockDim.x + threadIdx.x;
  if (idx >= 8*8*10*64) return;
  int lane = idx & 63;
  int kc = (idx >> 6) % 10;
  int jw = idx / 640;
  int tr = lane & 15, kg = lane >> 4;
  int grow = (tr&3)*256 + jw*4 + (tr>>2);
  int k0 = kc*32 + kg*8;
  half_t* d = dst + (size_t)idx*8;
#pragma unroll
  for (int jj=0;jj<8;jj++){
    int k = k0 + jj;
    float v = (k < 64) ? Wih[grow*64 + k] : Whh[grow*256 + (k - 64)];
    d[jj] = (half_t)v;
  }
}

// W1 blocks: [jw][kc 0..15][lane][8]; K = [h0(256) | h1(256)]
__global__ void prep_w1(const float* __restrict__ Wih, const float* __restrict__ Whh,
                        half_t* __restrict__ dst){
  int idx = blockIdx.x*blockDim.x + threadIdx.x;
  if (idx >= 8*8*16*64) return;
  int lane = idx & 63;
  int kc = (idx >> 6) & 15;
  int jw = idx >> 10;
  int tr = lane & 15, kg = lane >> 4;
  int grow = (tr&3)*256 + jw*4 + (tr>>2);
  int k0 = kc*32 + kg*8;
  half_t* d = dst + (size_t)idx*8;
#pragma unroll
  for (int jj=0;jj<8;jj++){
    int k = k0 + jj;
    float v = (k < 256) ? Wih[grow*256 + k] : Whh[grow*256 + (k - 256)];
    d[jj] = (half_t)v;
  }
}

// x -> [t][g 0..15][k8 0..7][b 0..15][8] fp16
__global__ void prep_x(const float* __restrict__ x, half_t* __restrict__ xblk){
  int idx = blockIdx.x*blockDim.x + threadIdx.x;
  if (idx >= 512*16*8*16) return;
  int b = idx & 15;
  int k8 = (idx >> 4) & 7;
  int g = (idx >> 7) & 15;
  int t = idx >> 11;
  const float* src = x + ((size_t)(g*16+b)*512 + (size_t)t)*64 + k8*8;
  half_t* d = xblk + (size_t)idx*8;
#pragma unroll
  for (int jj=0;jj<8;jj++) d[jj] = (half_t)src[jj];
}

// stamped-poll a 16 KB layer slice and stage packed fp16 into LDS fragment layout.
// task L = tid + i*512 handles the hh-pair (k8*8+2r, k8*8+2r+1) at column col:
//   k8=L>>6, col=(L>>2)&15, r=L&3
//   exchange words (wave-major layout e = jw*64 + kg*16 + col):
//     e_a = (k8*2 + (r>>1))*64 + ((2r)&3)*16 + col ; e_b = e_a + 16
//   LDS u32 word index = L exactly -> banks cycle 0..31 twice/wave = conflict-free,
//   one ds_write_b32 per task (was 2x ds_write_b16 at 4-way conflict).
__device__ __forceinline__ void poll_stage(const u32* s, half_t* sb, int tid, u32 want){
  int e_[4];
#pragma unroll
  for (int i = 0; i < 4; ++i){
    int L = tid + i*512;
    int k8 = L >> 6, col = (L >> 2) & 15, r = L & 3;
    e_[i] = (k8*2 + (r>>1))*64 + ((2*r)&3)*16 + col;
  }
  u32 va[4], vb[4];
  int ok = 0;
  for (int tries = 0; !ok && tries < (1<<20); ++tries){
    ok = 1;
#pragma unroll
    for (int i = 0; i < 4; ++i){
      va[i] = __hip_atomic_load(s + e_[i],      __ATOMIC_RELAXED, __HIP_MEMORY_SCOPE_AGENT);
      vb[i] = __hip_atomic_load(s + e_[i] + 16, __ATOMIC_RELAXED, __HIP_MEMORY_SCOPE_AGENT);
    }
#pragma unroll
    for (int i = 0; i < 4; ++i)
      ok &= (int)(((va[i] >> 16) >= want) & ((vb[i] >> 16) >= want));
  }
  u32* d = (u32*)sb;
#pragma unroll
  for (int i = 0; i < 4; ++i)
    d[tid + i*512] = (va[i] & 0xFFFFu) | ((vb[i] & 0xFFFFu) << 16);
}

// persistent distributed 2-layer LSTM: 16 groups x 8 WGs; WG owns 32 h x 16 batch
// exchange: per-value stamped u32 ((step+1)<<16 | fp16), wave-major coalesced stores
__global__ __launch_bounds__(THREADS, 1) void lstm_dist(
    const half_t* __restrict__ W0blk, const half_t* __restrict__ W1blk,
    const half_t* __restrict__ xblk,
    u32* __restrict__ h0x, u32* __restrict__ h1x,
    const float* __restrict__ b_ih0, const float* __restrict__ b_hh0,
    const float* __restrict__ b_ih1, const float* __restrict__ b_hh1,
    const float* __restrict__ W_head, const float* __restrict__ b_head,
    float* __restrict__ out)
{
  __shared__ __align__(16) half_t hbuf[2][8192];  // [slot][h0:4096 | h1:4096] halves

  const int tid = threadIdx.x;
  const int wave = tid >> 6, lane = tid & 63;
  const int lcol = lane & 15, kg = lane >> 4;
  const int bid = blockIdx.x;
  const int g = bid >> 3, j = bid & 7;
  const int jw = j*8 + wave;

  // ---- one-time: A-fragments + biases into registers ----
  half8 a0[10], a1[16];
#pragma unroll
  for (int kc = 0; kc < 10; ++kc)
    a0[kc] = *(const half8*)(W0blk + ((size_t)(jw*10 + kc)*64 + lane)*8);
#pragma unroll
  for (int kc = 0; kc < 16; ++kc)
    a1[kc] = *(const half8*)(W1blk + ((size_t)(jw*16 + kc)*64 + lane)*8);
#pragma unroll
  for (int kc = 0; kc < 10; ++kc) asm volatile("" : "+v"(a0[kc]));
#pragma unroll
  for (int kc = 0; kc < 16; ++kc) asm volatile("" : "+v"(a1[kc]));

  const int hh = jw*4 + kg;                 // lane's hidden index (0..255)
  const int eoff = jw*64 + lane;            // WAVE-MAJOR exchange u32 index
  f32x4 bias0, bias1;
#pragma unroll
  for (int ri = 0; ri < 4; ++ri){
    bias0[ri] = b_ih0[ri*256+hh] + b_hh0[ri*256+hh];
    bias1[ri] = b_ih1[ri*256+hh] + b_hh1[ri*256+hh];
  }

  // zero both LDS slots (serves as h0(-1)=h1(-1)=h1(-2)=0)
  for (int i = tid; i < 8192; i += THREADS) ((u32*)hbuf)[i] = 0u;

  float c0 = 0.f, c1 = 0.f;
  half8 xf0, xf1;
  {
    const half_t* xs = xblk + (size_t)g*1024;
    xf0 = *(const half8*)(xs + ((0*4+kg)*16 + lcol)*8);
    xf1 = *(const half8*)(xs + ((1*4+kg)*16 + lcol)*8);
  }
  __syncthreads();

  for (int q = 0; q <= TSTEPS; ++q){
    const int sslot = (q+1)&1, dslot = q&1;
    const u32 want = (u32)q;

    // ---- A) poll+stage h0(q-1) (poll IS the fetch; conflict-free staging) ----
    if (q > 0)
      poll_stage(h0x + (size_t)(sslot*GROUPS + g)*4096, hbuf[sslot], tid, want);
    __syncthreads();   // staged h0 visible; drains last phase's L1 stores (slot-reuse safe)

    const half_t* cb = hbuf[sslot];
    half8 h0f[8];
#pragma unroll
    for (int c = 0; c < 8; ++c)
      h0f[c] = *(const half8*)(cb + ((c*4+kg)*16 + lcol)*8);

    // ---- B) L0: step q (high prio: issue the coalesced h0 store ASAP) ----
    if (q < TSTEPS){
      __builtin_amdgcn_s_setprio(1);
      f32x4 acc = bias0;
      acc = __builtin_amdgcn_mfma_f32_16x16x32_f16(a0[0], xf0, acc, 0,0,0);
      acc = __builtin_amdgcn_mfma_f32_16x16x32_f16(a0[1], xf1, acc, 0,0,0);
#pragma unroll
      for (int c = 0; c < 8; ++c)
        acc = __builtin_amdgcn_mfma_f32_16x16x32_f16(a0[c+2], h0f[c], acc, 0,0,0);
      float ig=sigm(acc[0]), fg=sigm(acc[1]), gg=tanh_fast(acc[2]), og=sigm(acc[3]);
      c0 = fg*c0 + ig*gg;
      float hv = og*tanh_fast(c0);
      u32 sv = ((u32)(q+1) << 16) | (u32)__builtin_bit_cast(u16, (half_t)hv);
      __hip_atomic_store(h0x + (size_t)(dslot*GROUPS + g)*4096 + eoff, sv,
                         __ATOMIC_RELAXED, __HIP_MEMORY_SCOPE_AGENT);
      __builtin_amdgcn_s_setprio(0);
      __builtin_amdgcn_sched_barrier(0);   // issue the store before the h1 poll
    }

    // ---- C) poll+stage h1(q-2): overlaps producers' L1 of phase q-1 ----
    if (q > 1)
      poll_stage(h1x + (size_t)(sslot*GROUPS + g)*4096, hbuf[sslot] + 4096, tid, want);
    __syncthreads();   // drains this phase's L0 store too (overlapped with the poll)

    // ---- D) L1: step q-1 (high prio) ----
    if (q >= 1){
      __builtin_amdgcn_s_setprio(1);
      f32x4 acc = bias1;
#pragma unroll
      for (int c = 0; c < 8; ++c)
        acc = __builtin_amdgcn_mfma_f32_16x16x32_f16(a1[c], h0f[c], acc, 0,0,0);
#pragma unroll
      for (int c = 0; c < 8; ++c){
        half8 h1f = *(const half8*)(cb + 4096 + ((c*4+kg)*16 + lcol)*8);
        acc = __builtin_amdgcn_mfma_f32_16x16x32_f16(a1[c+8], h1f, acc, 0,0,0);
      }
      float ig=sigm(acc[0]), fg=sigm(acc[1]), gg=tanh_fast(acc[2]), og=sigm(acc[3]);
      c1 = fg*c1 + ig*gg;
      float hv = og*tanh_fast(c1);
      u32 sv = ((u32)(q+1) << 16) | (u32)__builtin_bit_cast(u16, (half_t)hv);
      __hip_atomic_store(h1x + (size_t)(dslot*GROUPS + g)*4096 + eoff, sv,
                         __ATOMIC_RELAXED, __HIP_MEMORY_SCOPE_AGENT);
      __builtin_amdgcn_s_setprio(0);
    }

    // ---- E) x prefetch for next phase (overlaps next poll) ----
    if (q+1 < TSTEPS){
      const half_t* xs = xblk + (size_t)((q+1)*16 + g)*1024;
      xf0 = *(const half8*)(xs + ((0*4+kg)*16 + lcol)*8);
      xf1 = *(const half8*)(xs + ((1*4+kg)*16 + lcol)*8);
    }
  }

  __syncthreads();

  // ---- head: poll final h1(511) (slot 0, stamp 513), stage, GEMV ----
  {
    poll_stage(h1x + (size_t)(0*GROUPS + g)*4096, hbuf[0], tid, (u32)(TSTEPS + 1));
    __syncthreads();

    if (tid < 240){
      int bl = 2*j + (tid >= 120 ? 1 : 0);
      int o = tid % 120;
      float s2 = b_head[o];
      const float* wr = W_head + (size_t)o*256;
#pragma unroll 4
      for (int k8 = 0; k8 < 32; ++k8){
        half8 hv = *(const half8*)(hbuf[0] + (k8*16 + bl)*8);
#pragma unroll
        for (int jj = 0; jj < 8; ++jj)
          s2 += (float)hv[jj] * wr[k8*8 + jj];
      }
      out[((size_t)(g*16 + bl))*120 + o] = s2;
    }
  }
}

extern "C" void kernel_launch(void* const* d_in, const int* in_sizes, int n_in,
                              void* d_out, int out_size, void* d_ws, size_t ws_size,
                              hipStream_t stream){
  const float* x     = (const float*)d_in[0];
  const float* W_ih0 = (const float*)d_in[1];
  const float* W_hh0 = (const float*)d_in[2];
  const float* b_ih0 = (const float*)d_in[3];
  const float* b_hh0 = (const float*)d_in[4];
  const float* W_ih1 = (const float*)d_in[5];
  const float* W_hh1 = (const float*)d_in[6];
  const float* b_ih1 = (const float*)d_in[7];
  const float* b_hh1 = (const float*)d_in[8];
  const float* W_head= (const float*)d_in[9];
  const float* b_head= (const float*)d_in[10];
  float* out = (float*)d_out;

  half_t* W0blk = (half_t*)d_ws;
  half_t* W1blk = W0blk + W0_HALVES;
  half_t* xblk  = W1blk + W1_HALVES;
  u32*    h0x   = (u32*)(xblk + X_HALVES);
  u32*    h1x   = h0x + HX_U32;

  // zero stamped exchange buffers every launch (graph-replay safe)
  (void)hipMemsetAsync(h0x, 0, (size_t)HX_U32*2*4, stream);   // h0x + h1x contiguous

  hipLaunchKernelGGL(prep_w0, dim3(160), dim3(256), 0, stream, W_ih0, W_hh0, W0blk);
  hipLaunchKernelGGL(prep_w1, dim3(256), dim3(256), 0, stream, W_ih1, W_hh1, W1blk);
  hipLaunchKernelGGL(prep_x,  dim3(4096), dim3(256), 0, stream, x, xblk);

  hipLaunchKernelGGL(lstm_dist, dim3(NWG), dim3(THREADS), 0, stream,
                     W0blk, W1blk, xblk, h0x, h1x,
                     b_ih0, b_hh0, b_ih1, b_hh1, W_head, b_head, out);
}

// Round 17
// 1471.702 us; speedup vs baseline: 1.1273x; 1.1273x over previous
//
#include <hip/hip_runtime.h>

typedef _Float16 half_t;
typedef _Float16 half8 __attribute__((ext_vector_type(8)));
typedef float f32x4 __attribute__((ext_vector_type(4)));
typedef unsigned long long u64;
typedef unsigned int u32;
typedef unsigned short u16;

#define GROUPS 16
#define WPG 8
#define NWG 128
#define THREADS 512
#define TSTEPS 512

// ws layout
#define W0_HALVES (8*8*10*64*8)    // 327680 halves
#define W1_HALVES (8*8*16*64*8)    // 524288 halves
#define X_HALVES  (512*16*1024)    // 8388608 halves
#define HX_U32    (2*GROUPS*4096)  // per layer: 2 slots x 16 groups x 4096 stamped u32

__device__ __forceinline__ float sigm(float x){ return 1.f/(1.f+__expf(-x)); }
__device__ __forceinline__ float tanh_fast(float x){ float e=__expf(2.f*x); return 1.f - 2.f/(e+1.f); }

// W0 blocks: [jw 0..63][kc 0..9][lane][8]; wave jw owns h [jw*4, jw*4+4)
__global__ void prep_w0(const float* __restrict__ Wih, const float* __restrict__ Whh,
                        half_t* __restrict__ dst){
  int idx = blockIdx.x*blockDim.x + threadIdx.x;
  if (idx >= 8*8*10*64) return;
  int lane = idx & 63;
  int kc = (idx >> 6) % 10;
  int jw = idx / 640;
  int tr = lane & 15, kg = lane >> 4;
  int grow = (tr&3)*256 + jw*4 + (tr>>2);
  int k0 = kc*32 + kg*8;
  half_t* d = dst + (size_t)idx*8;
#pragma unroll
  for (int jj=0;jj<8;jj++){
    int k = k0 + jj;
    float v = (k < 64) ? Wih[grow*64 + k] : Whh[grow*256 + (k - 64)];
    d[jj] = (half_t)v;
  }
}

// W1 blocks: [jw][kc 0..15][lane][8]; K = [h0(256) | h1(256)]
__global__ void prep_w1(const float* __restrict__ Wih, const float* __restrict__ Whh,
                        half_t* __restrict__ dst){
  int idx = blockIdx.x*blockDim.x + threadIdx.x;
  if (idx >= 8*8*16*64) return;
  int lane = idx & 63;
  int kc = (idx >> 6) & 15;
  int jw = idx >> 10;
  int tr = lane & 15, kg = lane >> 4;
  int grow = (tr&3)*256 + jw*4 + (tr>>2);
  int k0 = kc*32 + kg*8;
  half_t* d = dst + (size_t)idx*8;
#pragma unroll
  for (int jj=0;jj<8;jj++){
    int k = k0 + jj;
    float v = (k < 256) ? Wih[grow*256 + k] : Whh[grow*256 + (k - 256)];
    d[jj] = (half_t)v;
  }
}

// x -> [t][g 0..15][k8 0..7][b 0..15][8] fp16
__global__ void prep_x(const float* __restrict__ x, half_t* __restrict__ xblk){
  int idx = blockIdx.x*blockDim.x + threadIdx.x;
  if (idx >= 512*16*8*16) return;
  int b = idx & 15;
  int k8 = (idx >> 4) & 7;
  int g = (idx >> 7) & 15;
  int t = idx >> 11;
  const float* src = x + ((size_t)(g*16+b)*512 + (size_t)t)*64 + k8*8;
  half_t* d = xblk + (size_t)idx*8;
#pragma unroll
  for (int jj=0;jj<8;jj++) d[jj] = (half_t)src[jj];
}

// stamped-poll a 16 KB layer slice (coalesced u64 loads, = r15) and stage into
// LDS fragment layout with ONE conflict-free ds_write_b32 per u64 (= r16's goal).
// exchange permuted wave-major: e = jw*64 + lcol*4 + kg  (contiguous per wave).
// u64 m covers e=2m,2m+1 -> jw=m>>5, lcol=(m&31)>>1, c=m&1 -> hh pair (jw*4+2c, +1).
// LDS u32 index W = (jw>>1)*64 + lcol*4 + (jw&1)*2 + c   (banks: 2 lanes/bank = free).
__device__ __forceinline__ void poll_stage(const u64* s, half_t* sb, int tid, u32 want){
  u64 v[4];
  int ok = 0;
  for (int tries = 0; !ok && tries < (1<<20); ++tries){
    ok = 1;
#pragma unroll
    for (int i = 0; i < 4; ++i)
      v[i] = __hip_atomic_load(s + tid + i*512, __ATOMIC_RELAXED, __HIP_MEMORY_SCOPE_AGENT);
#pragma unroll
    for (int i = 0; i < 4; ++i)
      ok &= (int)((((u32)(v[i] >> 16) & 0xFFFFu) >= want) & (((u32)(v[i] >> 48)) >= want));
  }
  u32* d = (u32*)sb;
#pragma unroll
  for (int i = 0; i < 4; ++i){
    int m = tid + i*512;
    int jw2 = m >> 5, rem = m & 31, lc = rem >> 1, c = rem & 1;
    int W = (jw2 >> 1)*64 + lc*4 + (jw2 & 1)*2 + c;
    d[W] = ((u32)v[i] & 0xFFFFu) | (((u32)(v[i] >> 32) & 0xFFFFu) << 16);
  }
}

// persistent distributed 2-layer LSTM: 16 groups x 8 WGs; WG owns 32 h x 16 batch
// exchange: per-value stamped u32 ((step+1)<<16 | fp16), permuted wave-major stores
__global__ __launch_bounds__(THREADS, 1) void lstm_dist(
    const half_t* __restrict__ W0blk, const half_t* __restrict__ W1blk,
    const half_t* __restrict__ xblk,
    u32* __restrict__ h0x, u32* __restrict__ h1x,
    const float* __restrict__ b_ih0, const float* __restrict__ b_hh0,
    const float* __restrict__ b_ih1, const float* __restrict__ b_hh1,
    const float* __restrict__ W_head, const float* __restrict__ b_head,
    float* __restrict__ out)
{
  __shared__ __align__(16) half_t hbuf[2][8192];  // [slot][h0:4096 | h1:4096] halves

  const int tid = threadIdx.x;
  const int wave = tid >> 6, lane = tid & 63;
  const int lcol = lane & 15, kg = lane >> 4;
  const int bid = blockIdx.x;
  const int g = bid >> 3, j = bid & 7;
  const int jw = j*8 + wave;

  // ---- one-time: A-fragments + biases into registers ----
  half8 a0[10], a1[16];
#pragma unroll
  for (int kc = 0; kc < 10; ++kc)
    a0[kc] = *(const half8*)(W0blk + ((size_t)(jw*10 + kc)*64 + lane)*8);
#pragma unroll
  for (int kc = 0; kc < 16; ++kc)
    a1[kc] = *(const half8*)(W1blk + ((size_t)(jw*16 + kc)*64 + lane)*8);
#pragma unroll
  for (int kc = 0; kc < 10; ++kc) asm volatile("" : "+v"(a0[kc]));
#pragma unroll
  for (int kc = 0; kc < 16; ++kc) asm volatile("" : "+v"(a1[kc]));

  const int hh = jw*4 + kg;                 // lane's hidden index (0..255)
  const int eoff = jw*64 + lcol*4 + kg;     // permuted wave-major exchange u32 index
  f32x4 bias0, bias1;
#pragma unroll
  for (int ri = 0; ri < 4; ++ri){
    bias0[ri] = b_ih0[ri*256+hh] + b_hh0[ri*256+hh];
    bias1[ri] = b_ih1[ri*256+hh] + b_hh1[ri*256+hh];
  }

  // zero both LDS slots (serves as h0(-1)=h1(-1)=h1(-2)=0)
  for (int i = tid; i < 8192; i += THREADS) ((u32*)hbuf)[i] = 0u;

  float c0 = 0.f, c1 = 0.f;
  half8 xf0, xf1;
  {
    const half_t* xs = xblk + (size_t)g*1024;
    xf0 = *(const half8*)(xs + ((0*4+kg)*16 + lcol)*8);
    xf1 = *(const half8*)(xs + ((1*4+kg)*16 + lcol)*8);
  }
  __syncthreads();

  for (int q = 0; q <= TSTEPS; ++q){
    const int sslot = (q+1)&1, dslot = q&1;
    const u32 want = (u32)q;

    // ---- A) poll+stage h0(q-1) (coalesced poll IS the fetch) ----
    if (q > 0)
      poll_stage((const u64*)(h0x + (size_t)(sslot*GROUPS + g)*4096),
                 hbuf[sslot], tid, want);
    __syncthreads();   // staged h0 visible; drains last phase's L1 stores (slot-reuse safe)

    const half_t* cb = hbuf[sslot];
    half8 h0f[8];
#pragma unroll
    for (int c = 0; c < 8; ++c)
      h0f[c] = *(const half8*)(cb + ((c*4+kg)*16 + lcol)*8);

    // ---- B) L0: step q (high prio: issue the coalesced h0 store ASAP) ----
    if (q < TSTEPS){
      __builtin_amdgcn_s_setprio(1);
      f32x4 acc = bias0;
      acc = __builtin_amdgcn_mfma_f32_16x16x32_f16(a0[0], xf0, acc, 0,0,0);
      acc = __builtin_amdgcn_mfma_f32_16x16x32_f16(a0[1], xf1, acc, 0,0,0);
#pragma unroll
      for (int c = 0; c < 8; ++c)
        acc = __builtin_amdgcn_mfma_f32_16x16x32_f16(a0[c+2], h0f[c], acc, 0,0,0);
      float ig=sigm(acc[0]), fg=sigm(acc[1]), gg=tanh_fast(acc[2]), og=sigm(acc[3]);
      c0 = fg*c0 + ig*gg;
      float hv = og*tanh_fast(c0);
      u32 sv = ((u32)(q+1) << 16) | (u32)__builtin_bit_cast(u16, (half_t)hv);
      __hip_atomic_store(h0x + (size_t)(dslot*GROUPS + g)*4096 + eoff, sv,
                         __ATOMIC_RELAXED, __HIP_MEMORY_SCOPE_AGENT);
      __builtin_amdgcn_s_setprio(0);
      __builtin_amdgcn_sched_barrier(0);   // issue the store before the h1 poll
    }

    // ---- C) poll+stage h1(q-2): overlaps producers' L1 of phase q-1 ----
    if (q > 1)
      poll_stage((const u64*)(h1x + (size_t)(sslot*GROUPS + g)*4096),
                 hbuf[sslot] + 4096, tid, want);
    __syncthreads();   // drains this phase's L0 store too (overlapped with the poll)

    // ---- D) L1: step q-1 (high prio) ----
    if (q >= 1){
      __builtin_amdgcn_s_setprio(1);
      f32x4 acc = bias1;
#pragma unroll
      for (int c = 0; c < 8; ++c)
        acc = __builtin_amdgcn_mfma_f32_16x16x32_f16(a1[c], h0f[c], acc, 0,0,0);
#pragma unroll
      for (int c = 0; c < 8; ++c){
        half8 h1f = *(const half8*)(cb + 4096 + ((c*4+kg)*16 + lcol)*8);
        acc = __builtin_amdgcn_mfma_f32_16x16x32_f16(a1[c+8], h1f, acc, 0,0,0);
      }
      float ig=sigm(acc[0]), fg=sigm(acc[1]), gg=tanh_fast(acc[2]), og=sigm(acc[3]);
      c1 = fg*c1 + ig*gg;
      float hv = og*tanh_fast(c1);
      u32 sv = ((u32)(q+1) << 16) | (u32)__builtin_bit_cast(u16, (half_t)hv);
      __hip_atomic_store(h1x + (size_t)(dslot*GROUPS + g)*4096 + eoff, sv,
                         __ATOMIC_RELAXED, __HIP_MEMORY_SCOPE_AGENT);
      __builtin_amdgcn_s_setprio(0);
    }

    // ---- E) x prefetch for next phase (overlaps next poll) ----
    if (q+1 < TSTEPS){
      const half_t* xs = xblk + (size_t)((q+1)*16 + g)*1024;
      xf0 = *(const half8*)(xs + ((0*4+kg)*16 + lcol)*8);
      xf1 = *(const half8*)(xs + ((1*4+kg)*16 + lcol)*8);
    }
  }

  __syncthreads();

  // ---- head: poll final h1(511) (slot 0, stamp 513), stage, GEMV ----
  {
    poll_stage((const u64*)(h1x + (size_t)(0*GROUPS + g)*4096),
               hbuf[0], tid, (u32)(TSTEPS + 1));
    __syncthreads();

    if (tid < 240){
      int bl = 2*j + (tid >= 120 ? 1 : 0);
      int o = tid % 120;
      float s2 = b_head[o];
      const float* wr = W_head + (size_t)o*256;
#pragma unroll 4
      for (int k8 = 0; k8 < 32; ++k8){
        half8 hv = *(const half8*)(hbuf[0] + (k8*16 + bl)*8);
#pragma unroll
        for (int jj = 0; jj < 8; ++jj)
          s2 += (float)hv[jj] * wr[k8*8 + jj];
      }
      out[((size_t)(g*16 + bl))*120 + o] = s2;
    }
  }
}

extern "C" void kernel_launch(void* const* d_in, const int* in_sizes, int n_in,
                              void* d_out, int out_size, void* d_ws, size_t ws_size,
                              hipStream_t stream){
  const float* x     = (const float*)d_in[0];
  const float* W_ih0 = (const float*)d_in[1];
  const float* W_hh0 = (const float*)d_in[2];
  const float* b_ih0 = (const float*)d_in[3];
  const float* b_hh0 = (const float*)d_in[4];
  const float* W_ih1 = (const float*)d_in[5];
  const float* W_hh1 = (const float*)d_in[6];
  const float* b_ih1 = (const float*)d_in[7];
  const float* b_hh1 = (const float*)d_in[8];
  const float* W_head= (const float*)d_in[9];
  const float* b_head= (const float*)d_in[10];
  float* out = (float*)d_out;

  half_t* W0blk = (half_t*)d_ws;
  half_t* W1blk = W0blk + W0_HALVES;
  half_t* xblk  = W1blk + W1_HALVES;
  u32*    h0x   = (u32*)(xblk + X_HALVES);
  u32*    h1x   = h0x + HX_U32;

  // zero stamped exchange buffers every launch (graph-replay safe)
  (void)hipMemsetAsync(h0x, 0, (size_t)HX_U32*2*4, stream);   // h0x + h1x contiguous

  hipLaunchKernelGGL(prep_w0, dim3(160), dim3(256), 0, stream, W_ih0, W_hh0, W0blk);
  hipLaunchKernelGGL(prep_w1, dim3(256), dim3(256), 0, stream, W_ih1, W_hh1, W1blk);
  hipLaunchKernelGGL(prep_x,  dim3(4096), dim3(256), 0, stream, x, xblk);

  hipLaunchKernelGGL(lstm_dist, dim3(NWG), dim3(THREADS), 0, stream,
                     W0blk, W1blk, xblk, h0x, h1x,
                     b_ih0, b_hh0, b_ih1, b_hh1, W_head, b_head, out);
}